// Round 10
// baseline (77.273 us; speedup 1.0000x reference)
//
#include <hip/hip_runtime.h>

// Geometric product over 3D PGA, 16-component multivectors.
// C[..., k] = sum_ij A[...,i] * B[...,j] * cayley[k,i,j]
// Cayley table rebuilt at COMPILE TIME (mirrors the reference Python); the
// 16x16 double loop constant-folds to the 192 nonzero +-1 fp32 FMAs.
//
// R10: zero LDS, zero barriers, via an EXEC-SAFE DPP quad-transpose.
// R8's version failed because the dpp sat inside divergent ternaries:
// v_mov_dpp under a partial exec mask reads inactive partner lanes ->
// bound_ctrl/old value (0) -> all-zero output. Fix: select the value to
// SEND with cndmask, execute the dpp UNCONDITIONALLY (full exec), select
// the result with cndmask. 4 ops/pair, no divergence.
//   stage1 (lane^1, quad_perm [1,0,3,2]=0xB1):  mid[m0]@l0 = in[l0]@m0
//   stage2 (lane^2, quad_perm [2,3,0,1]=0x4E):  out[c]@q   = in[q]@c
// Element-chase check: in[3]@lane1 -> mid3@lane1 -> out[1]@lane3. OK.
// Layout: reg r @ lane l = quad(l&3) of MV 16r+(l>>2); after transpose,
// lane l owns all of MV 16*(l&3)+(l>>2); inverse transpose (involution)
// restores the coalesced store pattern. A and B use identical patterns so
// each lane's (a,b) pair is the same MV. NT stores kept (R7: -15us).

namespace {

typedef float f32x4 __attribute__((ext_vector_type(4)));

struct CayleyLUT {
    int idx[16][16];
    int sgn[16][16];
};

constexpr CayleyLUT make_lut() {
    CayleyLUT L{};
    constexpr int MASK[16] = {0, 2, 4, 8, 1, 6, 10, 12, 3, 5, 9, 14, 7, 11, 13, 15};
    constexpr int SIGN[16] = {1, 1, 1, 1, 1, 1, 1, 1, -1, -1, -1, 1, 1, 1, 1, -1};
    for (int i = 0; i < 16; ++i) {
        for (int j = 0; j < 16; ++j) {
            L.idx[i][j] = 0;
            L.sgn[i][j] = 0;
            if (MASK[i] & MASK[j] & 1) continue;  // shared null e0 -> vanishes
            const int rm = MASK[i] ^ MASK[j];
            int k = 0;
            for (int t = 0; t < 16; ++t)
                if (MASK[t] == rm) k = t;
            int s = 1;
            for (int bit = 0; bit < 4; ++bit) {
                if ((MASK[i] >> bit) & 1) {
                    int lower = MASK[j] & ((1 << bit) - 1);
                    int c = 0;
                    for (int x = lower; x; x >>= 1) c += x & 1;
                    if (c & 1) s = -s;
                }
            }
            L.idx[i][j] = k;
            L.sgn[i][j] = SIGN[i] * SIGN[j] * s * SIGN[k];
        }
    }
    return L;
}

constexpr CayleyLUT LUT = make_lut();

template <int CTRL>
__device__ __forceinline__ float dppf(float x) {
    return __int_as_float(
        __builtin_amdgcn_update_dpp(0, __float_as_int(x), CTRL, 0xF, 0xF, true));
}

// Exec-safe 4x4 transpose across the 4 lanes of a quad.
// On exit: x_c @ lane q == (entry x_q) @ lane c. Involution.
__device__ __forceinline__ void qtr(float& x0, float& x1, float& x2, float& x3,
                                    bool l0, bool l1) {
    // stage 1: exchange across lane^1 (dpp on FULL exec, selects around it)
    const float s01 = l0 ? x0 : x1;  // value this lane sends to lane^1
    const float s23 = l0 ? x2 : x3;
    const float r01 = dppf<0xB1>(s01);
    const float r23 = dppf<0xB1>(s23);
    const float m0 = l0 ? r01 : x0;
    const float m1 = l0 ? x1 : r01;
    const float m2 = l0 ? r23 : x2;
    const float m3 = l0 ? x3 : r23;
    // stage 2: exchange across lane^2
    const float s02 = l1 ? m0 : m2;
    const float s13 = l1 ? m1 : m3;
    const float r02 = dppf<0x4E>(s02);
    const float r13 = dppf<0x4E>(s13);
    x0 = l1 ? r02 : m0;
    x2 = l1 ? m2 : r02;
    x1 = l1 ? r13 : m1;
    x3 = l1 ? m3 : r13;
}

__device__ __forceinline__ void gp_compute(const float* a, const float* b, float* c) {
#pragma unroll
    for (int k = 0; k < 16; ++k) c[k] = 0.0f;
#pragma unroll
    for (int i = 0; i < 16; ++i) {
#pragma unroll
        for (int j = 0; j < 16; ++j) {
            const int s = LUT.sgn[i][j];
            if (s != 0) {
                const int k = LUT.idx[i][j];
                c[k] = fmaf(s > 0 ? a[i] : -a[i], b[j], c[k]);
            }
        }
    }
}

__global__ __launch_bounds__(256) void gp_kernel(const float* __restrict__ A,
                                                 const float* __restrict__ B,
                                                 float* __restrict__ C,
                                                 long long n_mv) {
    const int tid = threadIdx.x;
    const int lane = tid & 63;
    const long long wave_mv = (long long)blockIdx.x * 256 + (long long)((tid >> 6) << 6);
    if (wave_mv >= n_mv) return;  // wave-uniform
    const long long rem = n_mv - wave_mv;

    const f32x4* __restrict__ A4 = reinterpret_cast<const f32x4*>(A) + (wave_mv << 2);
    const f32x4* __restrict__ B4 = reinterpret_cast<const f32x4*>(B) + (wave_mv << 2);
    f32x4* __restrict__ C4 = reinterpret_cast<f32x4*>(C) + (wave_mv << 2);

    if (rem >= 64) {
        const bool l0 = (lane & 1) != 0;
        const bool l1 = (lane & 2) != 0;
        // ---- coalesced loads: reg r @ lane l = quad(l&3) of MV 16r+(l>>2)
        f32x4 av[4], bv[4];
#pragma unroll
        for (int r = 0; r < 4; ++r) {
            av[r] = A4[(r << 6) + lane];
            bv[r] = B4[(r << 6) + lane];
        }
        float a[16], b[16];
#pragma unroll
        for (int r = 0; r < 4; ++r) {
#pragma unroll
            for (int w = 0; w < 4; ++w) {
                a[4 * r + w] = av[r][w];
                b[4 * r + w] = bv[r][w];
            }
        }
        // ---- in-register transpose: lane now owns one full MV
#pragma unroll
        for (int w = 0; w < 4; ++w) {
            qtr(a[w], a[4 + w], a[8 + w], a[12 + w], l0, l1);
            qtr(b[w], b[4 + w], b[8 + w], b[12 + w], l0, l1);
        }
        float c[16];
        gp_compute(a, b, c);
        // ---- inverse transpose (same involution) + coalesced NT stores
#pragma unroll
        for (int w = 0; w < 4; ++w) {
            qtr(c[w], c[4 + w], c[8 + w], c[12 + w], l0, l1);
        }
#pragma unroll
        for (int r = 0; r < 4; ++r) {
            f32x4 v;
#pragma unroll
            for (int w = 0; w < 4; ++w) v[w] = c[4 * r + w];
            __builtin_nontemporal_store(v, &C4[(r << 6) + lane]);
        }
    } else {
        // ---- tail partial wave: direct per-lane I/O (tiny, uncoalesced ok)
        if (lane < (int)rem) {
            const long long m4 = (long long)lane << 2;
            float a[16], b[16];
#pragma unroll
            for (int q = 0; q < 4; ++q) {
                const f32x4 va = A4[m4 + q];
                const f32x4 vb = B4[m4 + q];
#pragma unroll
                for (int w = 0; w < 4; ++w) {
                    a[4 * q + w] = va[w];
                    b[4 * q + w] = vb[w];
                }
            }
            float c[16];
            gp_compute(a, b, c);
#pragma unroll
            for (int q = 0; q < 4; ++q) {
                f32x4 v;
#pragma unroll
                for (int w = 0; w < 4; ++w) v[w] = c[4 * q + w];
                C4[m4 + q] = v;
            }
        }
    }
}

}  // namespace

extern "C" void kernel_launch(void* const* d_in, const int* in_sizes, int n_in,
                              void* d_out, int out_size, void* d_ws, size_t ws_size,
                              hipStream_t stream) {
    const float* A = (const float*)d_in[0];
    const float* B = (const float*)d_in[1];
    float* C = (float*)d_out;
    const long long n_mv = (long long)in_sizes[0] / 16;
    const int nblocks = (int)((n_mv + 255) / 256);
    gp_kernel<<<nblocks, 256, 0, stream>>>(A, B, C, n_mv);
}

// Round 11
// 62.660 us; speedup vs baseline: 1.2332x; 1.2332x over previous
//
#include <hip/hip_runtime.h>

// Geometric product over 3D PGA, 16-component multivectors.
// C[..., k] = sum_ij A[...,i] * B[...,j] * cayley[k,i,j]
// Cayley table rebuilt at COMPILE TIME (mirrors the reference Python); the
// 16x16 double loop constant-folds to the 192 nonzero +-1 fp32 FMAs.
//
// R11 hybrid: R7's input path + R10's output path.
//   in : coalesced dwordx4 loads -> swizzled LDS -> ONE barrier -> b128 reads
//   out: DPP inverse quad-transpose in registers -> coalesced NT stores
// vs R7: -8 LDS ops/thread, -1 barrier (the whole output LDS round-trip and
// its vmcnt(0) drain were serial tail); +64 VALU (one transpose, not R10's 3).
// Lane mapping: lane l of wave w computes block-MV m = 64w + 16*(l&3)+(l>>2),
// so the R10 involution (proven on HW) emits reg r @ lane l = quad(l&3) of
// MV 16r+(l>>2) -> store index (w<<8)+(r<<6)+l is fully coalesced.
// New swizzle for the new compute pattern: slot(m,q)=m*16+((q^((m>>4)&3))<<2).
//   staging (m=f>>2,q=f&3): 8-lane phase = 4 even-m lanes (groups q^s in 0..3)
//     + 4 odd-m lanes (groups 4+q^s) -> 8 distinct 16B slots. OK
//   compute (m=64w+16c+g, q fixed): s(m)=c distinct across the 4 same-parity
//     lanes of each phase -> 8 distinct slots. OK
// Tail blocks: every lane runs the DPP (full exec); invalid-MV garbage is
// masked by the f<nf4 store guard. R7 lesson: NT stores (keep). R5: all
// global I/O coalesced. R8 lesson: never put dpp inside divergent selects.

namespace {

typedef float f32x4 __attribute__((ext_vector_type(4)));

struct CayleyLUT {
    int idx[16][16];
    int sgn[16][16];
};

constexpr CayleyLUT make_lut() {
    CayleyLUT L{};
    constexpr int MASK[16] = {0, 2, 4, 8, 1, 6, 10, 12, 3, 5, 9, 14, 7, 11, 13, 15};
    constexpr int SIGN[16] = {1, 1, 1, 1, 1, 1, 1, 1, -1, -1, -1, 1, 1, 1, 1, -1};
    for (int i = 0; i < 16; ++i) {
        for (int j = 0; j < 16; ++j) {
            L.idx[i][j] = 0;
            L.sgn[i][j] = 0;
            if (MASK[i] & MASK[j] & 1) continue;  // shared null e0 -> vanishes
            const int rm = MASK[i] ^ MASK[j];
            int k = 0;
            for (int t = 0; t < 16; ++t)
                if (MASK[t] == rm) k = t;
            int s = 1;
            for (int bit = 0; bit < 4; ++bit) {
                if ((MASK[i] >> bit) & 1) {
                    int lower = MASK[j] & ((1 << bit) - 1);
                    int c = 0;
                    for (int x = lower; x; x >>= 1) c += x & 1;
                    if (c & 1) s = -s;
                }
            }
            L.idx[i][j] = k;
            L.sgn[i][j] = SIGN[i] * SIGN[j] * s * SIGN[k];
        }
    }
    return L;
}

constexpr CayleyLUT LUT = make_lut();

__device__ __forceinline__ int slot(int m, int q) {
    // Float offset of quad q of MV m in the swizzled LDS tile (see header).
    return m * 16 + ((q ^ ((m >> 4) & 3)) << 2);
}

template <int CTRL>
__device__ __forceinline__ float dppf(float x) {
    return __int_as_float(
        __builtin_amdgcn_update_dpp(0, __float_as_int(x), CTRL, 0xF, 0xF, true));
}

// Exec-safe 4x4 transpose across the 4 lanes of a quad (proven on HW, R10).
// On exit: x_c @ lane-pos q == (entry x_q) @ lane-pos c. Involution.
__device__ __forceinline__ void qtr(float& x0, float& x1, float& x2, float& x3,
                                    bool l0, bool l1) {
    const float s01 = l0 ? x0 : x1;
    const float s23 = l0 ? x2 : x3;
    const float r01 = dppf<0xB1>(s01);  // quad_perm [1,0,3,2]
    const float r23 = dppf<0xB1>(s23);
    const float m0 = l0 ? r01 : x0;
    const float m1 = l0 ? x1 : r01;
    const float m2 = l0 ? r23 : x2;
    const float m3 = l0 ? x3 : r23;
    const float s02 = l1 ? m0 : m2;
    const float s13 = l1 ? m1 : m3;
    const float r02 = dppf<0x4E>(s02);  // quad_perm [2,3,0,1]
    const float r13 = dppf<0x4E>(s13);
    x0 = l1 ? r02 : m0;
    x2 = l1 ? m2 : r02;
    x1 = l1 ? r13 : m1;
    x3 = l1 ? m3 : r13;
}

__device__ __forceinline__ void gp_compute(const float* a, const float* b, float* c) {
#pragma unroll
    for (int k = 0; k < 16; ++k) c[k] = 0.0f;
#pragma unroll
    for (int i = 0; i < 16; ++i) {
#pragma unroll
        for (int j = 0; j < 16; ++j) {
            const int s = LUT.sgn[i][j];
            if (s != 0) {
                const int k = LUT.idx[i][j];
                c[k] = fmaf(s > 0 ? a[i] : -a[i], b[j], c[k]);
            }
        }
    }
}

__global__ __launch_bounds__(256) void gp_kernel(const float* __restrict__ A,
                                                 const float* __restrict__ B,
                                                 float* __restrict__ C,
                                                 long long n_mv) {
    __shared__ float sA[256 * 16];  // 16 KiB
    __shared__ float sB[256 * 16];  // 16 KiB
    const int t = threadIdx.x;
    const int w = t >> 6;
    const int lane = t & 63;
    const long long base_mv = (long long)blockIdx.x * 256;
    const bool full = (base_mv + 256 <= n_mv);
    const int mv_here = full ? 256 : (int)(n_mv - base_mv);
    const int nf4 = mv_here * 4;

    const f32x4* __restrict__ A4 = reinterpret_cast<const f32x4*>(A) + base_mv * 4;
    const f32x4* __restrict__ B4 = reinterpret_cast<const f32x4*>(B) + base_mv * 4;
    f32x4* __restrict__ C4 = reinterpret_cast<f32x4*>(C) + base_mv * 4;

    // ---- stage in: coalesced loads, swizzled LDS scatter ----
    if (full) {
#pragma unroll
        for (int r = 0; r < 4; ++r) {
            const int f = t + 256 * r;
            const f32x4 va = A4[f];
            const f32x4 vb = B4[f];
            const int o = slot(f >> 2, f & 3);
            *reinterpret_cast<f32x4*>(&sA[o]) = va;
            *reinterpret_cast<f32x4*>(&sB[o]) = vb;
        }
    } else {
#pragma unroll
        for (int r = 0; r < 4; ++r) {
            const int f = t + 256 * r;
            if (f < nf4) {
                const f32x4 va = A4[f];
                const f32x4 vb = B4[f];
                const int o = slot(f >> 2, f & 3);
                *reinterpret_cast<f32x4*>(&sA[o]) = va;
                *reinterpret_cast<f32x4*>(&sB[o]) = vb;
            }
        }
    }
    __syncthreads();  // the ONLY barrier

    // ---- compute: lane l of wave w owns block-MV 64w + 16*(l&3) + (l>>2) ----
    const int m = (w << 6) + ((lane & 3) << 4) + (lane >> 2);  // always < 256
    float a[16], b[16];
#pragma unroll
    for (int q = 0; q < 4; ++q) {
        const f32x4 va = *reinterpret_cast<const f32x4*>(&sA[slot(m, q)]);
        const f32x4 vb = *reinterpret_cast<const f32x4*>(&sB[slot(m, q)]);
#pragma unroll
        for (int x = 0; x < 4; ++x) {
            a[4 * q + x] = va[x];
            b[4 * q + x] = vb[x];
        }
    }
    float c[16];
    gp_compute(a, b, c);

    // ---- output: DPP inverse transpose (full exec, no divergence) ----
    const bool l0 = (lane & 1) != 0;
    const bool l1 = (lane & 2) != 0;
#pragma unroll
    for (int x = 0; x < 4; ++x) {
        qtr(c[x], c[4 + x], c[8 + x], c[12 + x], l0, l1);
    }
    // reg r @ lane l now holds quad(l&3) of MV 16r+(l>>2) (wave tile)
    // -> coalesced NT stores at f = (w<<8) + (r<<6) + lane
    if (full) {
#pragma unroll
        for (int r = 0; r < 4; ++r) {
            f32x4 v;
#pragma unroll
            for (int x = 0; x < 4; ++x) v[x] = c[4 * r + x];
            __builtin_nontemporal_store(v, &C4[(w << 8) + (r << 6) + lane]);
        }
    } else {
#pragma unroll
        for (int r = 0; r < 4; ++r) {
            const int f = (w << 8) + (r << 6) + lane;
            if (f < nf4) {
                f32x4 v;
#pragma unroll
                for (int x = 0; x < 4; ++x) v[x] = c[4 * r + x];
                __builtin_nontemporal_store(v, &C4[f]);
            }
        }
    }
}

}  // namespace

extern "C" void kernel_launch(void* const* d_in, const int* in_sizes, int n_in,
                              void* d_out, int out_size, void* d_ws, size_t ws_size,
                              hipStream_t stream) {
    const float* A = (const float*)d_in[0];
    const float* B = (const float*)d_in[1];
    float* C = (float*)d_out;
    const long long n_mv = (long long)in_sizes[0] / 16;
    const int nblocks = (int)((n_mv + 255) / 256);
    gp_kernel<<<nblocks, 256, 0, stream>>>(A, B, C, n_mv);
}